// Round 13
// baseline (273.775 us; speedup 1.0000x reference)
//
#include <hip/hip_runtime.h>
#include <hip/hip_bf16.h>
#include <math.h>

// Problem constants (fixed by setup_inputs)
#define BB 2
#define HH 8
#define LQ 512
#define LK 512
#define DD 32
#define D2 (DD / 2)      // 16 d-pairs
#define C2 2             // d-pairs per LDS chunk (chunk = 4 d's = 16 KB)
#define NC (D2 / C2)     // 8 chunks
#define WAVES 8          // waves per block (512 threads)
#define RPW 2            // q-rows per wave
#define ROWSPB (WAVES * RPW)  // 16 rows per block

#define LOG2E 1.44269504088896f

static __device__ __forceinline__ float fast_rcp(float x) {
#if __has_builtin(__builtin_amdgcn_rcpf)
  return __builtin_amdgcn_rcpf(x);
#else
  return 1.0f / x;
#endif
}

static __device__ __forceinline__ float fast_exp2(float x) {
#if __has_builtin(__builtin_amdgcn_exp2f)
  return __builtin_amdgcn_exp2f(x);
#else
  return __expf(x * 0.69314718056f);
#endif
}

static __device__ __forceinline__ float rfl(float x) {
  // wave-uniform value -> SGPR (frees VGPRs + vector operand slots)
  return __int_as_float(__builtin_amdgcn_readfirstlane(__float_as_int(x)));
}

// ---------------------------------------------------------------------------
// Pre-kernel (transposing, d-pair packed):
//   wst4[bh][d2][kk] = {e^-k(2d2), k(2d2)*a(2d2), e^-k(2d2+1), k(2d2+1)*a(2d2+1)}
// ---------------------------------------------------------------------------
__global__ __launch_bounds__(256) void gatv2_prek_p(
    const float* __restrict__ k, const float* __restrict__ att,
    float4* __restrict__ wst4) {
  const int bh = blockIdx.x >> 3;          // 0..15
  const int kt = blockIdx.x & 7;           // kk tile of 64
  const int h = bh & (HH - 1);
  const int t = threadIdx.x;

  __shared__ float tile[64][33];           // +1 pad

  const float4* src = (const float4*)(k + ((size_t)bh * LK + kt * 64) * DD);
#pragma unroll
  for (int i = 0; i < 2; ++i) {
    const int idx = t + i * 256;           // 0..511
    const float4 v = src[idx];
    const int kkl = idx >> 3;
    const int d4 = (idx & 7) * 4;
    tile[kkl][d4 + 0] = v.x; tile[kkl][d4 + 1] = v.y;
    tile[kkl][d4 + 2] = v.z; tile[kkl][d4 + 3] = v.w;
  }
  __syncthreads();

  const int d2 = t >> 4;                   // 0..15
  const int kl0 = (t & 15) * 4;
  const float a0 = att[h * DD + 2 * d2 + 0];
  const float a1 = att[h * DD + 2 * d2 + 1];
  float4* dst = wst4 + ((size_t)bh * D2 + d2) * LK + kt * 64 + kl0;
#pragma unroll
  for (int j = 0; j < 4; ++j) {
    const float k0 = tile[kl0 + j][2 * d2 + 0];
    const float k1 = tile[kl0 + j][2 * d2 + 1];
    float4 o;
    o.x = fast_exp2(-k0 * LOG2E); o.y = k0 * a0;
    o.z = fast_exp2(-k1 * LOG2E); o.w = k1 * a1;
    dst[j] = o;
  }
}

// ---------------------------------------------------------------------------
// Main kernel (R11 structure + batched rcp + SGPR consts):
// 8 waves/block, 2 q-rows per wave (16 rows/block, same bh).
// Per (row, c, chunk): 4 d's -> ONE v_rcp via 4-way product trick.
// ---------------------------------------------------------------------------
__global__ __launch_bounds__(512) void gatv2_main_b4(
    const float* __restrict__ q, const int* __restrict__ mask,
    const float* __restrict__ bias, const float* __restrict__ att,
    const float4* __restrict__ wst4, float* __restrict__ out) {
  const int lane = threadIdx.x & 63;
  const int wid = threadIdx.x >> 6;        // 0..7
  const int tid = threadIdx.x;             // 0..511
  const int rowbase = blockIdx.x * ROWSPB; // multiple of 16 -> same bh
  const int bh = rowbase >> 9;
  const int b = rowbase >> 12;
  const int h = bh & (HH - 1);

  __shared__ float4 lds4[2][C2 * LK];      // 2 x 16 KB data
  __shared__ float4 cst4[ROWSPB][D2];      // 4 KB row constants {Eq,qa}x2 per d-pair

  const float4* __restrict__ kb = wst4 + (size_t)bh * (D2 * LK);

  // stage chunk 0 (global -> reg)
  float4 s0 = kb[tid];
  float4 s1 = kb[tid + 512];

  // row constants: row rw = wid*RPW + (lane>>5), d = lane&31 (all 64 lanes busy)
  {
    const int rw = wid * RPW + (lane >> 5);
    const int d = lane & 31;
    const float qd = q[(size_t)(rowbase + rw) * DD + d];
    const float ad = att[h * DD + d];
    float2 c;
    c.x = fast_exp2(-qd * LOG2E);          // e^{-q_d}
    c.y = qd * ad;                         // q_d * a_d
    ((float2*)cst4)[rw * DD + d] = c;
  }
  lds4[0][tid] = s0;
  lds4[0][tid + 512] = s1;

  float acc[RPW][8];
#pragma unroll
  for (int j = 0; j < RPW; ++j)
#pragma unroll
    for (int c = 0; c < 8; ++c) acc[j][c] = 0.0f;

#pragma unroll
  for (int cc = 0; cc < NC; ++cc) {
    __syncthreads();                       // chunk cc staged by all threads

    if (cc + 1 < NC) {                     // issue next-chunk loads early
      const float4* src = kb + (size_t)(cc + 1) * (C2 * LK);
      s0 = src[tid];
      s1 = src[tid + 512];
    }

    // wave-uniform row constants for this chunk's 4 d's -> SGPRs
    const float4 vA0 = cst4[wid * RPW + 0][cc * 2 + 0];
    const float4 vB0 = cst4[wid * RPW + 0][cc * 2 + 1];
    const float4 vA1 = cst4[wid * RPW + 1][cc * 2 + 0];
    const float4 vB1 = cst4[wid * RPW + 1][cc * 2 + 1];
    const float eq00 = rfl(vA0.x), qa00 = rfl(vA0.y), eq01 = rfl(vA0.z), qa01 = rfl(vA0.w);
    const float eq02 = rfl(vB0.x), qa02 = rfl(vB0.y), eq03 = rfl(vB0.z), qa03 = rfl(vB0.w);
    const float eq10 = rfl(vA1.x), qa10 = rfl(vA1.y), eq11 = rfl(vA1.z), qa11 = rfl(vA1.w);
    const float eq12 = rfl(vB1.x), qa12 = rfl(vB1.y), eq13 = rfl(vB1.z), qa13 = rfl(vB1.w);

    const float4* __restrict__ buf = lds4[cc & 1];
#pragma unroll
    for (int c = 0; c < 8; ++c) {
      const float4 p0 = buf[lane + 64 * c];       // d-pair A {Ek,ka,Ek,ka}
      const float4 p1 = buf[LK + lane + 64 * c];  // d-pair B
      // ---- row 0: one rcp for 4 elements ----
      {
        const float u0 = fmaf(eq00, p0.x, 1.0f);
        const float u1 = fmaf(eq01, p0.z, 1.0f);
        const float u2 = fmaf(eq02, p1.x, 1.0f);
        const float u3 = fmaf(eq03, p1.z, 1.0f);
        const float t0 = qa00 + p0.y;
        const float t1 = qa01 + p0.w;
        const float t2 = qa02 + p1.y;
        const float t3 = qa03 + p1.w;
        const float m01 = u0 * u1;
        const float m23 = u2 * u3;
        const float r = fast_rcp(m01 * m23);
        const float r01 = r * m23;               // ~1/(u0*u1)
        const float r23 = r * m01;               // ~1/(u2*u3)
        float a = acc[0][c];
        a = fmaf(t0, r01 * u1, a);
        a = fmaf(t1, r01 * u0, a);
        a = fmaf(t2, r23 * u3, a);
        a = fmaf(t3, r23 * u2, a);
        acc[0][c] = a;
      }
      // ---- row 1 ----
      {
        const float u0 = fmaf(eq10, p0.x, 1.0f);
        const float u1 = fmaf(eq11, p0.z, 1.0f);
        const float u2 = fmaf(eq12, p1.x, 1.0f);
        const float u3 = fmaf(eq13, p1.z, 1.0f);
        const float t0 = qa10 + p0.y;
        const float t1 = qa11 + p0.w;
        const float t2 = qa12 + p1.y;
        const float t3 = qa13 + p1.w;
        const float m01 = u0 * u1;
        const float m23 = u2 * u3;
        const float r = fast_rcp(m01 * m23);
        const float r01 = r * m23;
        const float r23 = r * m01;
        float a = acc[1][c];
        a = fmaf(t0, r01 * u1, a);
        a = fmaf(t1, r01 * u0, a);
        a = fmaf(t2, r23 * u3, a);
        a = fmaf(t3, r23 * u2, a);
        acc[1][c] = a;
      }
    }

    if (cc + 1 < NC) {                     // write next chunk after compute
      float4* dst = lds4[(cc + 1) & 1];
      dst[tid] = s0;
      dst[tid + 512] = s1;
    }
  }

  // --- epilogue: per-row bias+mask, masked softmax, store ---
#pragma unroll
  for (int j = 0; j < RPW; ++j) {
    const int r = rowbase + wid * RPW + j;
    const int qi = r & (LQ - 1);
    const float* __restrict__ brow = bias + (size_t)r * LK;
    const int* __restrict__ mrow = mask + ((size_t)(b * LQ + qi)) * LK;

    float sc[8];
#pragma unroll
    for (int c = 0; c < 8; ++c) {
      const float bval = brow[lane + 64 * c];
      const int mval = mrow[lane + 64 * c];
      sc[c] = mval ? -INFINITY : (acc[j][c] + bval);
    }

    float m = sc[0];
#pragma unroll
    for (int c = 1; c < 8; ++c) m = fmaxf(m, sc[c]);
#pragma unroll
    for (int off = 32; off > 0; off >>= 1)
      m = fmaxf(m, __shfl_xor(m, off, 64));

    float sum = 0.0f;
#pragma unroll
    for (int c = 0; c < 8; ++c) {
      const float p = fast_exp2((sc[c] - m) * LOG2E);
      sc[c] = p;
      sum += p;
    }
#pragma unroll
    for (int off = 32; off > 0; off >>= 1)
      sum += __shfl_xor(sum, off, 64);

    const bool dead = (m == -INFINITY);
    const float inv = dead ? 0.0f : fast_rcp(sum);

    float* __restrict__ orow = out + (size_t)r * LK;
#pragma unroll
    for (int c = 0; c < 8; ++c) {
      orow[lane + 64 * c] = dead ? 0.0f : sc[c] * inv;
    }
  }
}

// ---------------------------------------------------------------------------
// Fallback (proven R2 kernel) in case ws_size < 2 MB.
// ---------------------------------------------------------------------------
__global__ __launch_bounds__(256) void gatv2_fallback(
    const float* __restrict__ q, const float* __restrict__ k,
    const int* __restrict__ mask, const float* __restrict__ bias,
    const float* __restrict__ att, float* __restrict__ out) {
  const int lane = threadIdx.x & 63;
  const int wid = threadIdx.x >> 6;
  const int r = blockIdx.x * 4 + wid;
  const int b = r >> 12;
  const int h = (r >> 9) & (HH - 1);
  const int qi = r & (LQ - 1);

  const float* __restrict__ qrow = q + (size_t)r * DD;
  const float* __restrict__ kbase = k + ((size_t)(b * HH + h)) * (size_t)(LK * DD);
  const float* __restrict__ arow = att + h * DD;
  const float* __restrict__ brow = bias + (size_t)r * LK;
  const int* __restrict__ mrow = mask + ((size_t)(b * LQ + qi)) * LK;

  float qv[DD], av[DD];
#pragma unroll
  for (int d0 = 0; d0 < DD; d0 += 4) {
    const float4 qq = *(const float4*)(qrow + d0);
    const float4 aa = *(const float4*)(arow + d0);
    qv[d0 + 0] = qq.x; qv[d0 + 1] = qq.y; qv[d0 + 2] = qq.z; qv[d0 + 3] = qq.w;
    av[d0 + 0] = aa.x; av[d0 + 1] = aa.y; av[d0 + 2] = aa.z; av[d0 + 3] = aa.w;
  }

  float sc[8];
#pragma unroll
  for (int c = 0; c < 8; ++c) {
    const int kk = lane + 64 * c;
    const float* __restrict__ kr = kbase + (size_t)kk * DD;
    const float bval = brow[kk];
    const int mval = mrow[kk];
    float acc = 0.0f;
#pragma unroll
    for (int d0 = 0; d0 < DD; d0 += 4) {
      const float4 kv = *(const float4*)(kr + d0);
      const float kvf[4] = {kv.x, kv.y, kv.z, kv.w};
#pragma unroll
      for (int j = 0; j < 4; ++j) {
        const float t = qv[d0 + j] + kvf[j];
        const float e = fast_exp2(t * -LOG2E);
        const float sg = fast_rcp(1.0f + e);
        acc = fmaf(t * sg, av[d0 + j], acc);
      }
    }
    const float s = acc + bval;
    sc[c] = mval ? -INFINITY : s;
  }

  float m = sc[0];
#pragma unroll
  for (int c = 1; c < 8; ++c) m = fmaxf(m, sc[c]);
#pragma unroll
  for (int off = 32; off > 0; off >>= 1)
    m = fmaxf(m, __shfl_xor(m, off, 64));

  float sum = 0.0f;
#pragma unroll
  for (int c = 0; c < 8; ++c) {
    const float p = fast_exp2((sc[c] - m) * LOG2E);
    sc[c] = p;
    sum += p;
  }
#pragma unroll
  for (int off = 32; off > 0; off >>= 1)
    sum += __shfl_xor(sum, off, 64);

  const bool dead = (m == -INFINITY);
  const float inv = dead ? 0.0f : fast_rcp(sum);

  float* __restrict__ orow = out + (size_t)r * LK;
#pragma unroll
  for (int c = 0; c < 8; ++c) {
    orow[lane + 64 * c] = dead ? 0.0f : sc[c] * inv;
  }
}

extern "C" void kernel_launch(void* const* d_in, const int* in_sizes, int n_in,
                              void* d_out, int out_size, void* d_ws, size_t ws_size,
                              hipStream_t stream) {
  const float* q = (const float*)d_in[0];
  const float* k = (const float*)d_in[1];
  // d_in[2] = scale, unused
  const int* mask = (const int*)d_in[3];
  const float* bias = (const float*)d_in[4];
  const float* att = (const float*)d_in[5];
  float* out = (float*)d_out;

  const int rows = BB * HH * LQ;                          // 8192
  const size_t ws_needed = (size_t)BB * HH * D2 * LK * sizeof(float4);  // 2 MB

  if (ws_size >= ws_needed) {
    float4* wst4 = (float4*)d_ws;
    gatv2_prek_p<<<dim3(128), dim3(256), 0, stream>>>(k, att, wst4);
    gatv2_main_b4<<<dim3(rows / ROWSPB), dim3(64 * WAVES), 0, stream>>>(
        q, mask, bias, att, wst4, out);
  } else {
    gatv2_fallback<<<dim3(rows / 4), dim3(256), 0, stream>>>(q, k, mask, bias, att, out);
  }
}

// Round 14
// 116.577 us; speedup vs baseline: 2.3484x; 2.3484x over previous
//
#include <hip/hip_runtime.h>
#include <hip/hip_bf16.h>
#include <math.h>

// Problem constants (fixed by setup_inputs)
#define BB 2
#define HH 8
#define LQ 512
#define LK 512
#define DD 32

#define LOG2E 1.44269504088896f

static __device__ __forceinline__ float fast_rcp(float x) {
#if __has_builtin(__builtin_amdgcn_rcpf)
  return __builtin_amdgcn_rcpf(x);
#else
  return 1.0f / x;
#endif
}

static __device__ __forceinline__ float fast_exp2(float x) {
#if __has_builtin(__builtin_amdgcn_exp2f)
  return __builtin_amdgcn_exp2f(x);
#else
  return __expf(x * 0.69314718056f);
#endif
}

// ===========================================================================
// PATH 1 (ws >= 20 MB): 2-kernel split, register-resident k-fragments.
// ws layout: [0,2MB) ktab float2[16][32][512] {Ek,ka}
//            [2MB,4MB) qtab float2[8192][32] {Eq,qa}
//            [4MB,20MB) scores float[8192][512]
// ===========================================================================

// --- prekK: transpose k into ktab[bh][d][kk] = {e^-k, k*a} (proven in R5/R6)
__global__ __launch_bounds__(256) void gatv2_prek_t(
    const float* __restrict__ k, const float* __restrict__ att,
    float2* __restrict__ ktab) {
  const int bh = blockIdx.x >> 3;          // 0..15
  const int kt = blockIdx.x & 7;           // kk tile of 64
  const int h = bh & (HH - 1);
  const int t = threadIdx.x;

  __shared__ float tile[64][33];           // +1 pad: conflict-free transpose

  const float4* src = (const float4*)(k + ((size_t)bh * LK + kt * 64) * DD);
#pragma unroll
  for (int i = 0; i < 2; ++i) {
    const int idx = t + i * 256;           // 0..511
    const float4 v = src[idx];
    const int kkl = idx >> 3;
    const int d4 = (idx & 7) * 4;
    tile[kkl][d4 + 0] = v.x; tile[kkl][d4 + 1] = v.y;
    tile[kkl][d4 + 2] = v.z; tile[kkl][d4 + 3] = v.w;
  }
  __syncthreads();

  const int d = t >> 3;                    // 0..31
  const int kl0 = (t & 7) * 8;             // 0..56
  const float a = att[h * DD + d];
  float2* dst = ktab + ((size_t)bh * DD + d) * LK + kt * 64 + kl0;
#pragma unroll
  for (int j = 0; j < 8; ++j) {
    const float kv = tile[kl0 + j][d];
    float2 o;
    o.x = fast_exp2(-kv * LOG2E);
    o.y = kv * a;
    dst[j] = o;
  }
}

// --- prekQ: qtab[row][d] = {e^-q, q*a}
__global__ __launch_bounds__(256) void gatv2_prek_q(
    const float* __restrict__ q, const float* __restrict__ att,
    float2* __restrict__ qtab) {
  const int idx = blockIdx.x * 256 + threadIdx.x;  // 0..262143
  const int row = idx >> 5;
  const int d = idx & 31;
  const int h = (row >> 9) & (HH - 1);
  const float qd = q[idx];                 // q layout is [row][d] = idx
  const float ad = att[h * DD + d];
  float2 c;
  c.x = fast_exp2(-qd * LOG2E);
  c.y = qd * ad;
  qtab[idx] = c;
}

// --- scoreA: each lane owns one column; k-frag in 64 VGPRs, reused 16 rows.
// No LDS, no barriers. grid 1024 x 256 threads.
__global__ __launch_bounds__(256) void gatv2_score(
    const float2* __restrict__ ktab, const float2* __restrict__ qtab,
    const float* __restrict__ bias, const int* __restrict__ mask,
    float* __restrict__ scores) {
  const int lane = threadIdx.x & 63;
  const int w = threadIdx.x >> 6;          // 0..3
  const int bid = blockIdx.x;              // 0..1023
  const int bh = bid >> 6;                 // 0..15
  const int rem = bid & 63;
  const int rg = rem >> 1;                 // 0..31 (16-row group)
  const int ch = rem & 1;                  // column half
  const int col = ch * 256 + w * 64 + lane;       // 0..511
  const int row0 = bh * LQ + rg * 16;             // global row base
  const int b = bh >> 3;

  // k-fragment: 32 x {Ek, ka} for this lane's column (coalesced over lanes)
  const float2* __restrict__ kcol = ktab + (size_t)bh * (DD * LK) + col;
  float2 kf[DD];
#pragma unroll
  for (int d = 0; d < DD; ++d) kf[d] = kcol[(size_t)d * LK];

#pragma unroll 2
  for (int rr = 0; rr < 16; ++rr) {
    const int row = row0 + rr;             // wave-uniform
    const float2* __restrict__ qrow = qtab + (size_t)row * DD;  // uniform -> s_load
    float acc = 0.0f;
#pragma unroll
    for (int d = 0; d < DD; ++d) {
      const float2 qc = qrow[d];
      const float u = fmaf(qc.x, kf[d].x, 1.0f);
      const float t = qc.y + kf[d].y;
      acc = fmaf(t, fast_rcp(u), acc);
    }
    const int qi = row & (LQ - 1);
    const float bval = bias[(size_t)row * LK + col];
    const int mval = mask[((size_t)(b * LQ + qi)) * LK + col];
    scores[(size_t)row * LK + col] = mval ? -INFINITY : (acc + bval);
  }
}

// --- softmaxB: one wave per row (proven epilogue structure).
__global__ __launch_bounds__(256) void gatv2_softmax(
    const float* __restrict__ scores, float* __restrict__ out) {
  const int lane = threadIdx.x & 63;
  const int wid = threadIdx.x >> 6;
  const int r = blockIdx.x * 4 + wid;      // 0..8191

  const float* __restrict__ srow = scores + (size_t)r * LK;
  float sc[8];
#pragma unroll
  for (int c = 0; c < 8; ++c) sc[c] = srow[lane + 64 * c];

  float m = sc[0];
#pragma unroll
  for (int c = 1; c < 8; ++c) m = fmaxf(m, sc[c]);
#pragma unroll
  for (int off = 32; off > 0; off >>= 1)
    m = fmaxf(m, __shfl_xor(m, off, 64));

  float sum = 0.0f;
#pragma unroll
  for (int c = 0; c < 8; ++c) {
    const float p = fast_exp2((sc[c] - m) * LOG2E);
    sc[c] = p;
    sum += p;
  }
#pragma unroll
  for (int off = 32; off > 0; off >>= 1)
    sum += __shfl_xor(sum, off, 64);

  const bool dead = (m == -INFINITY);
  const float inv = dead ? 0.0f : fast_rcp(sum);

  float* __restrict__ orow = out + (size_t)r * LK;
#pragma unroll
  for (int c = 0; c < 8; ++c) {
    orow[lane + 64 * c] = dead ? 0.0f : sc[c] * inv;
  }
}

// ===========================================================================
// PATH 2 (2 MB <= ws < 20 MB): proven R11 kernels (verbatim).
// ===========================================================================
#define D2 (DD / 2)
#define C2 2
#define NC (D2 / C2)
#define WAVES 8
#define RPW 2
#define ROWSPB (WAVES * RPW)

__global__ __launch_bounds__(256) void gatv2_prek_p(
    const float* __restrict__ k, const float* __restrict__ att,
    float4* __restrict__ wst4) {
  const int bh = blockIdx.x >> 3;
  const int kt = blockIdx.x & 7;
  const int h = bh & (HH - 1);
  const int t = threadIdx.x;

  __shared__ float tile[64][33];

  const float4* src = (const float4*)(k + ((size_t)bh * LK + kt * 64) * DD);
#pragma unroll
  for (int i = 0; i < 2; ++i) {
    const int idx = t + i * 256;
    const float4 v = src[idx];
    const int kkl = idx >> 3;
    const int d4 = (idx & 7) * 4;
    tile[kkl][d4 + 0] = v.x; tile[kkl][d4 + 1] = v.y;
    tile[kkl][d4 + 2] = v.z; tile[kkl][d4 + 3] = v.w;
  }
  __syncthreads();

  const int d2 = t >> 4;
  const int kl0 = (t & 15) * 4;
  const float a0 = att[h * DD + 2 * d2 + 0];
  const float a1 = att[h * DD + 2 * d2 + 1];
  float4* dst = wst4 + ((size_t)bh * D2 + d2) * LK + kt * 64 + kl0;
#pragma unroll
  for (int j = 0; j < 4; ++j) {
    const float k0 = tile[kl0 + j][2 * d2 + 0];
    const float k1 = tile[kl0 + j][2 * d2 + 1];
    float4 o;
    o.x = fast_exp2(-k0 * LOG2E); o.y = k0 * a0;
    o.z = fast_exp2(-k1 * LOG2E); o.w = k1 * a1;
    dst[j] = o;
  }
}

__global__ __launch_bounds__(512) void gatv2_main_r2(
    const float* __restrict__ q, const int* __restrict__ mask,
    const float* __restrict__ bias, const float* __restrict__ att,
    const float4* __restrict__ wst4, float* __restrict__ out) {
  const int lane = threadIdx.x & 63;
  const int wid = threadIdx.x >> 6;
  const int tid = threadIdx.x;
  const int rowbase = blockIdx.x * ROWSPB;
  const int bh = rowbase >> 9;
  const int b = rowbase >> 12;
  const int h = bh & (HH - 1);

  __shared__ float4 lds4[2][C2 * LK];
  __shared__ float4 cst4[ROWSPB][D2];

  const float4* __restrict__ kb = wst4 + (size_t)bh * (D2 * LK);

  float4 s0 = kb[tid];
  float4 s1 = kb[tid + 512];

  {
    const int rw = wid * RPW + (lane >> 5);
    const int d = lane & 31;
    const float qd = q[(size_t)(rowbase + rw) * DD + d];
    const float ad = att[h * DD + d];
    float2 c;
    c.x = fast_exp2(-qd * LOG2E);
    c.y = qd * ad;
    ((float2*)cst4)[rw * DD + d] = c;
  }
  lds4[0][tid] = s0;
  lds4[0][tid + 512] = s1;

  float acc[RPW][8];
#pragma unroll
  for (int j = 0; j < RPW; ++j)
#pragma unroll
    for (int c = 0; c < 8; ++c) acc[j][c] = 0.0f;

  float bv[RPW][8];
  int mv[RPW][8];

#pragma unroll
  for (int cc = 0; cc < NC; ++cc) {
    __syncthreads();

    float4 s0n, s1n;
    if (cc + 1 < NC) {
      const float4* src = kb + (size_t)(cc + 1) * (C2 * LK);
      s0n = src[tid];
      s1n = src[tid + 512];
    } else {
      const float* __restrict__ brow = bias + (size_t)rowbase * LK;
      const int* __restrict__ mrow = mask + ((size_t)(b * LQ) + (rowbase & (LQ - 1))) * LK;
#pragma unroll
      for (int j = 0; j < RPW; ++j) {
        const int rw = wid * RPW + j;
#pragma unroll
        for (int c = 0; c < 8; ++c) {
          bv[j][c] = brow[(size_t)rw * LK + lane + 64 * c];
          mv[j][c] = mrow[(size_t)rw * LK + lane + 64 * c];
        }
      }
    }

    const float4 c0A = cst4[wid * RPW + 0][cc * 2 + 0];
    const float4 c0B = cst4[wid * RPW + 0][cc * 2 + 1];
    const float4 c1A = cst4[wid * RPW + 1][cc * 2 + 0];
    const float4 c1B = cst4[wid * RPW + 1][cc * 2 + 1];

    const float4* __restrict__ buf = lds4[cc & 1];
#pragma unroll
    for (int d2l = 0; d2l < C2; ++d2l) {
      const float4 k0 = d2l ? c0B : c0A;
      const float4 k1 = d2l ? c1B : c1A;
      const float4* __restrict__ pd = buf + d2l * LK + lane;
#pragma unroll
      for (int c = 0; c < 8; ++c) {
        const float4 p = pd[64 * c];
        float u = fmaf(k0.x, p.x, 1.0f);
        float t = k0.y + p.y;
        acc[0][c] = fmaf(t, fast_rcp(u), acc[0][c]);
        u = fmaf(k0.z, p.z, 1.0f);
        t = k0.w + p.w;
        acc[0][c] = fmaf(t, fast_rcp(u), acc[0][c]);
        u = fmaf(k1.x, p.x, 1.0f);
        t = k1.y + p.y;
        acc[1][c] = fmaf(t, fast_rcp(u), acc[1][c]);
        u = fmaf(k1.z, p.z, 1.0f);
        t = k1.w + p.w;
        acc[1][c] = fmaf(t, fast_rcp(u), acc[1][c]);
      }
    }

    if (cc + 1 < NC) {
      float4* dst = lds4[(cc + 1) & 1];
      dst[tid] = s0n;
      dst[tid + 512] = s1n;
    }
  }

#pragma unroll
  for (int j = 0; j < RPW; ++j) {
    const int r = rowbase + wid * RPW + j;

    float sc[8];
#pragma unroll
    for (int c = 0; c < 8; ++c)
      sc[c] = mv[j][c] ? -INFINITY : (acc[j][c] + bv[j][c]);

    float m = sc[0];
#pragma unroll
    for (int c = 1; c < 8; ++c) m = fmaxf(m, sc[c]);
#pragma unroll
    for (int off = 32; off > 0; off >>= 1)
      m = fmaxf(m, __shfl_xor(m, off, 64));

    float sum = 0.0f;
#pragma unroll
    for (int c = 0; c < 8; ++c) {
      const float p = fast_exp2((sc[c] - m) * LOG2E);
      sc[c] = p;
      sum += p;
    }
#pragma unroll
    for (int off = 32; off > 0; off >>= 1)
      sum += __shfl_xor(sum, off, 64);

    const bool dead = (m == -INFINITY);
    const float inv = dead ? 0.0f : fast_rcp(sum);

    float* __restrict__ orow = out + (size_t)r * LK;
#pragma unroll
    for (int c = 0; c < 8; ++c) {
      orow[lane + 64 * c] = dead ? 0.0f : sc[c] * inv;
    }
  }
}

// ===========================================================================
// PATH 3: R2 fallback (no workspace).
// ===========================================================================
__global__ __launch_bounds__(256) void gatv2_fallback(
    const float* __restrict__ q, const float* __restrict__ k,
    const int* __restrict__ mask, const float* __restrict__ bias,
    const float* __restrict__ att, float* __restrict__ out) {
  const int lane = threadIdx.x & 63;
  const int wid = threadIdx.x >> 6;
  const int r = blockIdx.x * 4 + wid;
  const int b = r >> 12;
  const int h = (r >> 9) & (HH - 1);
  const int qi = r & (LQ - 1);

  const float* __restrict__ qrow = q + (size_t)r * DD;
  const float* __restrict__ kbase = k + ((size_t)(b * HH + h)) * (size_t)(LK * DD);
  const float* __restrict__ arow = att + h * DD;
  const float* __restrict__ brow = bias + (size_t)r * LK;
  const int* __restrict__ mrow = mask + ((size_t)(b * LQ + qi)) * LK;

  float qv[DD], av[DD];
#pragma unroll
  for (int d0 = 0; d0 < DD; d0 += 4) {
    const float4 qq = *(const float4*)(qrow + d0);
    const float4 aa = *(const float4*)(arow + d0);
    qv[d0 + 0] = qq.x; qv[d0 + 1] = qq.y; qv[d0 + 2] = qq.z; qv[d0 + 3] = qq.w;
    av[d0 + 0] = aa.x; av[d0 + 1] = aa.y; av[d0 + 2] = aa.z; av[d0 + 3] = aa.w;
  }

  float sc[8];
#pragma unroll
  for (int c = 0; c < 8; ++c) {
    const int kk = lane + 64 * c;
    const float* __restrict__ kr = kbase + (size_t)kk * DD;
    const float bval = brow[kk];
    const int mval = mrow[kk];
    float acc = 0.0f;
#pragma unroll
    for (int d0 = 0; d0 < DD; d0 += 4) {
      const float4 kv = *(const float4*)(kr + d0);
      const float kvf[4] = {kv.x, kv.y, kv.z, kv.w};
#pragma unroll
      for (int j = 0; j < 4; ++j) {
        const float t = qv[d0 + j] + kvf[j];
        const float e = fast_exp2(t * -LOG2E);
        const float sg = fast_rcp(1.0f + e);
        acc = fmaf(t * sg, av[d0 + j], acc);
      }
    }
    const float s = acc + bval;
    sc[c] = mval ? -INFINITY : s;
  }

  float m = sc[0];
#pragma unroll
  for (int c = 1; c < 8; ++c) m = fmaxf(m, sc[c]);
#pragma unroll
  for (int off = 32; off > 0; off >>= 1)
    m = fmaxf(m, __shfl_xor(m, off, 64));

  float sum = 0.0f;
#pragma unroll
  for (int c = 0; c < 8; ++c) {
    const float p = fast_exp2((sc[c] - m) * LOG2E);
    sc[c] = p;
    sum += p;
  }
#pragma unroll
  for (int off = 32; off > 0; off >>= 1)
    sum += __shfl_xor(sum, off, 64);

  const bool dead = (m == -INFINITY);
  const float inv = dead ? 0.0f : fast_rcp(sum);

  float* __restrict__ orow = out + (size_t)r * LK;
#pragma unroll
  for (int c = 0; c < 8; ++c) {
    orow[lane + 64 * c] = dead ? 0.0f : sc[c] * inv;
  }
}

extern "C" void kernel_launch(void* const* d_in, const int* in_sizes, int n_in,
                              void* d_out, int out_size, void* d_ws, size_t ws_size,
                              hipStream_t stream) {
  const float* q = (const float*)d_in[0];
  const float* k = (const float*)d_in[1];
  // d_in[2] = scale, unused
  const int* mask = (const int*)d_in[3];
  const float* bias = (const float*)d_in[4];
  const float* att = (const float*)d_in[5];
  float* out = (float*)d_out;

  const int rows = BB * HH * LQ;                               // 8192
  const size_t ktab_b = (size_t)BB * HH * DD * LK * sizeof(float2);   // 2 MB
  const size_t qtab_b = (size_t)rows * DD * sizeof(float2);           // 2 MB
  const size_t scores_b = (size_t)rows * LK * sizeof(float);          // 16 MB

  if (ws_size >= ktab_b + qtab_b + scores_b) {
    char* wsb = (char*)d_ws;
    float2* ktab = (float2*)wsb;
    float2* qtab = (float2*)(wsb + ktab_b);
    float* scores = (float*)(wsb + ktab_b + qtab_b);

    gatv2_prek_t<<<dim3(128), dim3(256), 0, stream>>>(k, att, ktab);
    gatv2_prek_q<<<dim3(1024), dim3(256), 0, stream>>>(q, att, qtab);
    gatv2_score<<<dim3(1024), dim3(256), 0, stream>>>(ktab, qtab, bias, mask, scores);
    gatv2_softmax<<<dim3(rows / 4), dim3(256), 0, stream>>>(scores, out);
  } else if (ws_size >= (size_t)BB * HH * D2 * LK * sizeof(float4)) {
    float4* wst4 = (float4*)d_ws;
    gatv2_prek_p<<<dim3(128), dim3(256), 0, stream>>>(k, att, wst4);
    gatv2_main_r2<<<dim3(rows / ROWSPB), dim3(64 * WAVES), 0, stream>>>(
        q, mask, bias, att, wst4, out);
  } else {
    gatv2_fallback<<<dim3(rows / 4), dim3(256), 0, stream>>>(q, k, mask, bias, att, out);
  }
}